// Round 9
// baseline (10722.750 us; speedup 1.0000x reference)
//
#include <hip/hip_runtime.h>

#define B_ 256
#define S_ 512
#define E_ 128
#define H_ 256
#define FH_ 1024
#define HROW 264  // 256 + 8 pad (shorts) -> row pitch 132 dwords = 4 mod 32, conflict-free

typedef __bf16 bf16x8 __attribute__((ext_vector_type(8)));
typedef float f32x4 __attribute__((ext_vector_type(4)));
typedef unsigned short u16x4 __attribute__((ext_vector_type(4)));
typedef unsigned short u16x8 __attribute__((ext_vector_type(8)));

__device__ __forceinline__ unsigned short f2bf(float f) {
  union { float f; unsigned int u; } a; a.f = f;
  unsigned int u = a.u;
  u += 0x7fffu + ((u >> 16) & 1u);  // RNE
  return (unsigned short)(u >> 16);
}
__device__ __forceinline__ float bf2f(unsigned short v) {
  union { unsigned int u; float f; } a; a.u = ((unsigned int)v) << 16;
  return a.f;
}
__device__ __forceinline__ float sigm(float x) { return 1.f / (1.f + __expf(-x)); }
__device__ __forceinline__ float tanh_(float x) {
  float e = __expf(2.f * x);
  return 1.f - 2.f / (e + 1.f);
}

// ---------------- workspace layout (bytes) ----------------
#define OFF_ENC    ((size_t)0)          // enc_out bf16 [256][512][256]  67108864
#define OFF_WHHE   ((size_t)67108864)   // enc_Whh bf16 [1024][256]        524288
#define OFF_WHHP   ((size_t)67633152)   // pb_Whh  bf16                    524288
#define OFF_WREF   ((size_t)68157440)   // Wref    bf16 [256][256]         131072
#define OFF_MENC   ((size_t)68288512)   // M = enc_Wih@W_emb f32 [1024][2]   8192
#define OFF_BIASE  ((size_t)68296704)   // enc_bih+enc_bhh f32 [1024]        4096
#define OFF_XPV    ((size_t)68300800)   // pb x-projection f32 [1024]        4096
#define OFF_FLAGS  ((size_t)68304896)   // u32 flags (unused by k1)          1024
#define OFF_HX     ((size_t)68305920)   // (unused)                        262144
#define OFF_HFIN   ((size_t)68568064)   // final h f32 [256][256]          262144
#define OFF_QBUF   ((size_t)68830208)   // q f32 [256][256]                262144
#define OFF_UBUF   ((size_t)69092352)   // u f32 [256][512]                524288

// ---------------- K0: prep (weight conversion, folded projections, zeroing) ----
__global__ void k0_prep(const float* __restrict__ eWih, const float* __restrict__ eWhh,
                        const float* __restrict__ ebih, const float* __restrict__ ebhh,
                        const float* __restrict__ pWih, const float* __restrict__ pWhh,
                        const float* __restrict__ pbih, const float* __restrict__ pbhh,
                        const float* __restrict__ W_emb, const float* __restrict__ dec_in,
                        const float* __restrict__ Wref,
                        unsigned short* __restrict__ WhhE, unsigned short* __restrict__ WhhP,
                        unsigned short* __restrict__ Wrefb,
                        float* __restrict__ Menc, float* __restrict__ biasE,
                        float* __restrict__ xpv,
                        unsigned int* __restrict__ flags, float* __restrict__ ubuf) {
  int gid = blockIdx.x * blockDim.x + threadIdx.x;
  int NT = gridDim.x * blockDim.x;
  for (int i = gid; i < FH_ * H_; i += NT) {
    WhhE[i] = f2bf(eWhh[i]);
    WhhP[i] = f2bf(pWhh[i]);
  }
  for (int i = gid; i < H_ * H_; i += NT) Wrefb[i] = f2bf(Wref[i]);
  for (int i = gid; i < B_ * S_; i += NT) ubuf[i] = 0.f;
  if (gid < 256) flags[gid] = 0u;
  if (gid < FH_) {
    int n = gid;
    float m0 = 0.f, m1 = 0.f, xs = 0.f;
    for (int e = 0; e < E_; ++e) {
      float w = eWih[n * E_ + e];
      m0 += w * W_emb[e * 2 + 0];
      m1 += w * W_emb[e * 2 + 1];
      xs += pWih[n * E_ + e] * dec_in[e];
    }
    Menc[n * 2 + 0] = m0;
    Menc[n * 2 + 1] = m1;
    biasE[n] = ebih[n] + ebhh[n];
    xpv[n] = xs + pbih[n] + pbhh[n];
  }
}

// ---------------- K1: fully self-contained LSTM recurrence ----------------
// 16 WGs x 512 threads: ONE WG per 16-row batch group, owning ALL 1024 gate
// columns. Full Whh (512KB bf16) = 1KB/thread = 256 AGPRs, pinned via "+a"
// asm and consumed DIRECTLY from AGPRs by inline-asm v_mfma ("a" operand) --
// no VGPR copies, no remat, no spill (AGPR demand = 256 = cap, VGPR ~130).
// Wave w owns h-columns [32w, 32w+32) x 4 gates: 2 col-blocks x 4 gates x
// 8 k-chunks = 64 MFMAs/step. h exchange is a pure-LDS double buffer with
// ONE __syncthreads per step. ZERO cross-WG traffic (rounds 0-8 proved the
// cross-WG handshake costs 2-3k cy/step no matter the atomic flavor).
// enc_out staged in a 128KB LDS ring, flushed coalesced every 16 steps, so
// steps carry no outstanding global stores into the barrier's vmcnt drain.
__launch_bounds__(512, 1)
__global__ void k1_lstm(const float* __restrict__ inp,
                        const unsigned short* __restrict__ WhhE,
                        const unsigned short* __restrict__ WhhP,
                        const float* __restrict__ Menc, const float* __restrict__ biasE,
                        const float* __restrict__ xpv,
                        unsigned short* __restrict__ enc_out,
                        float* __restrict__ hfin) {
  __shared__ unsigned short hbuf[2][16 * HROW];   // h bf16 double buffer
  __shared__ unsigned short ebuf[16][16][256];    // enc_out 16-step ring, 128KB
  __shared__ float xin[2][16][2];
  const int tid = threadIdx.x;
  const int wave = tid >> 6, lane = tid & 63, quad = lane >> 4, l16 = lane & 15;
  const int grp = blockIdx.x;      // batch group 0..15
  const int col0 = wave * 32;      // this wave's first h column

  for (int i = tid; i < 2 * 16 * HROW; i += 512) hbuf[0][i] = 0;
  if (tid < 32)
    xin[0][tid >> 1][tid & 1] = inp[((grp * 16 + (tid >> 1)) * S_ + 0) * 2 + (tid & 1)];

  float c0[4] = {0.f, 0.f, 0.f, 0.f}, c1[4] = {0.f, 0.f, 0.f, 0.f};
  float hf0[4] = {0.f, 0.f, 0.f, 0.f}, hf1[4] = {0.f, 0.f, 0.f, 0.f};
  float m0c[2][4], m1c[2][4], bcc[2][4];

  // 64 named weight fragments: W{cb}{g}{kt}, 4 AGPRs each = 256 AGPRs.
#define WDECL(cb, g) f32x4 W##cb##g##0, W##cb##g##1, W##cb##g##2, W##cb##g##3, \
                           W##cb##g##4, W##cb##g##5, W##cb##g##6, W##cb##g##7
  WDECL(0, 0); WDECL(0, 1); WDECL(0, 2); WDECL(0, 3);
  WDECL(1, 0); WDECL(1, 1); WDECL(1, 2); WDECL(1, 3);
#undef WDECL
  const f32x4 z4 = {0.f, 0.f, 0.f, 0.f};
  __syncthreads();

  int t = 0;
#pragma unroll 1
  for (int phase = 0; phase < 2; ++phase) {
    const unsigned short* Wsrc = phase ? WhhP : WhhE;
#define WLOAD(cb, g)                                                               \
    {                                                                              \
      const unsigned short* wp = Wsrc + ((g) * 256 + col0 + (cb) * 16 + l16) * H_  \
                                 + quad * 8;                                       \
      W##cb##g##0 = *(const f32x4*)(wp + 0 * 32);                                  \
      W##cb##g##1 = *(const f32x4*)(wp + 1 * 32);                                  \
      W##cb##g##2 = *(const f32x4*)(wp + 2 * 32);                                  \
      W##cb##g##3 = *(const f32x4*)(wp + 3 * 32);                                  \
      W##cb##g##4 = *(const f32x4*)(wp + 4 * 32);                                  \
      W##cb##g##5 = *(const f32x4*)(wp + 5 * 32);                                  \
      W##cb##g##6 = *(const f32x4*)(wp + 6 * 32);                                  \
      W##cb##g##7 = *(const f32x4*)(wp + 7 * 32);                                  \
    }
    WLOAD(0, 0) WLOAD(0, 1) WLOAD(0, 2) WLOAD(0, 3)
    WLOAD(1, 0) WLOAD(1, 1) WLOAD(1, 2) WLOAD(1, 3)
#undef WLOAD
    // Pin into AGPRs (opaque asm results: cannot be rematerialized).
    asm volatile(""
                 : "+a"(W000), "+a"(W001), "+a"(W002), "+a"(W003),
                   "+a"(W004), "+a"(W005), "+a"(W006), "+a"(W007),
                   "+a"(W010), "+a"(W011), "+a"(W012), "+a"(W013),
                   "+a"(W014), "+a"(W015), "+a"(W016), "+a"(W017),
                   "+a"(W020), "+a"(W021), "+a"(W022), "+a"(W023),
                   "+a"(W024), "+a"(W025), "+a"(W026), "+a"(W027),
                   "+a"(W030), "+a"(W031), "+a"(W032), "+a"(W033),
                   "+a"(W034), "+a"(W035), "+a"(W036), "+a"(W037));
    asm volatile(""
                 : "+a"(W100), "+a"(W101), "+a"(W102), "+a"(W103),
                   "+a"(W104), "+a"(W105), "+a"(W106), "+a"(W107),
                   "+a"(W110), "+a"(W111), "+a"(W112), "+a"(W113),
                   "+a"(W114), "+a"(W115), "+a"(W116), "+a"(W117),
                   "+a"(W120), "+a"(W121), "+a"(W122), "+a"(W123),
                   "+a"(W124), "+a"(W125), "+a"(W126), "+a"(W127),
                   "+a"(W130), "+a"(W131), "+a"(W132), "+a"(W133),
                   "+a"(W134), "+a"(W135), "+a"(W136), "+a"(W137));
#pragma unroll
    for (int cb = 0; cb < 2; ++cb)
#pragma unroll
      for (int g = 0; g < 4; ++g) {
        int n = g * 256 + col0 + cb * 16 + l16;
        if (phase == 0) {
          m0c[cb][g] = Menc[n * 2 + 0]; m1c[cb][g] = Menc[n * 2 + 1];
          bcc[cb][g] = biasE[n];
        } else {
          m0c[cb][g] = 0.f; m1c[cb][g] = 0.f; bcc[cb][g] = xpv[n];
        }
      }

#pragma unroll 1
    for (int step = 0; step < 512; ++step, ++t) {
      const int cur = t & 1, nxt = cur ^ 1;
      const unsigned short* hbc = &hbuf[cur][0];
      unsigned short* hbn = &hbuf[nxt][0];
      // ---- prefetch next x (latency hides under GEMM) ----
      float xpre = 0.f;
      if (phase == 0 && tid < 32) {
        int sN = (step < 511) ? step + 1 : 511;
        xpre = inp[((grp * 16 + (tid >> 1)) * S_ + sN) * 2 + (tid & 1)];
      }
      // ---- GEMM: 8 tiles (2 col-blocks x 4 gates), K=256 ----
      f32x4 a00 = z4, a01 = z4, a02 = z4, a03 = z4;
      f32x4 a10 = z4, a11 = z4, a12 = z4, a13 = z4;
#define MF(acc, af, w)                                                \
      asm volatile("v_mfma_f32_16x16x32_bf16 %0, %1, %2, %0"          \
                   : "+v"(acc) : "v"(af), "a"(w))
#define MM(kt)                                                                  \
      {                                                                         \
        bf16x8 Af = *(const bf16x8*)(hbc + l16 * HROW + kt * 32 + quad * 8);    \
        MF(a00, Af, W00##kt); MF(a01, Af, W01##kt);                             \
        MF(a02, Af, W02##kt); MF(a03, Af, W03##kt);                             \
        MF(a10, Af, W10##kt); MF(a11, Af, W11##kt);                             \
        MF(a12, Af, W12##kt); MF(a13, Af, W13##kt);                             \
      }
      MM(0) MM(1) MM(2) MM(3) MM(4) MM(5) MM(6) MM(7)
#undef MM
#undef MF
      // MFMA->VALU hazard cover; also orders acc reads after the MFMAs.
      asm volatile("s_nop 7\n\ts_nop 7\n\ts_nop 7"
                   : "+v"(a00), "+v"(a01), "+v"(a02), "+v"(a03),
                     "+v"(a10), "+v"(a11), "+v"(a12), "+v"(a13));
      // ---- gates: lane owns rows quad*4+r, cols col0+cb*16+l16 ----
      unsigned short hb0[4], hb1[4];
#define GATES(cb, ACC0, ACC1, ACC2, ACC3, CC, HF, HB)                           \
      _Pragma("unroll")                                                         \
      for (int r = 0; r < 4; ++r) {                                             \
        int m = quad * 4 + r;                                                   \
        float x0 = xin[cur][m][0], x1 = xin[cur][m][1];                         \
        float gi = ACC0[r] + x0 * m0c[cb][0] + x1 * m1c[cb][0] + bcc[cb][0];    \
        float gf = ACC1[r] + x0 * m0c[cb][1] + x1 * m1c[cb][1] + bcc[cb][1];    \
        float gc = ACC2[r] + x0 * m0c[cb][2] + x1 * m1c[cb][2] + bcc[cb][2];    \
        float go = ACC3[r] + x0 * m0c[cb][3] + x1 * m1c[cb][3] + bcc[cb][3];    \
        float cn = sigm(gf) * CC[r] + sigm(gi) * tanh_(gc);                     \
        CC[r] = cn;                                                             \
        HF[r] = sigm(go) * tanh_(cn);                                           \
        HB[r] = f2bf(HF[r]);                                                    \
      }
      GATES(0, a00, a01, a02, a03, c0, hf0, hb0)
      GATES(1, a10, a11, a12, a13, c1, hf1, hb1)
#undef GATES
      // ---- write h(t+1) into the other LDS buffer; stage enc_out in LDS ----
#pragma unroll
      for (int r = 0; r < 4; ++r) {
        int row = quad * 4 + r;
        hbn[row * HROW + col0 + l16] = hb0[r];
        hbn[row * HROW + col0 + 16 + l16] = hb1[r];
        if (phase == 0) {
          ebuf[t & 15][row][col0 + l16] = hb0[r];
          ebuf[t & 15][row][col0 + 16 + l16] = hb1[r];
        }
      }
      if (phase == 0 && tid < 32) xin[nxt][tid >> 1][tid & 1] = xpre;
      __syncthreads();  // h(t+1) + ebuf slice visible to all waves
      // ---- coalesced enc_out flush every 16 steps ----
      if (phase == 0 && (step & 15) == 15) {
        int ss = tid >> 5;           // 0..15 step slot
        int row = (tid >> 1) & 15;   // 0..15 batch row
        int halfc = tid & 1;         // column half
        const unsigned short* src = &ebuf[ss][row][halfc * 128];
        unsigned short* dst = enc_out +
            ((size_t)(grp * 16 + row) * S_ + (size_t)(step - 15 + ss)) * H_ + halfc * 128;
#pragma unroll
        for (int i = 0; i < 16; ++i)
          *(u16x8*)(dst + i * 8) = *(const u16x8*)(src + i * 8);
        __syncthreads();  // ebuf free before next step overwrites slot 0
      }
    }
  }
  // final h (fp32) for the attention query
#pragma unroll
  for (int r = 0; r < 4; ++r) {
    int row = grp * 16 + quad * 4 + r;
    hfin[row * H_ + col0 + l16] = hf0[r];
    hfin[row * H_ + col0 + 16 + l16] = hf1[r];
  }
}

// ---------------- K1b: q = h @ Wq^T + bq (fp32) ----------------
__global__ void k1b_q(const float* __restrict__ hfin, const float* __restrict__ Wq,
                      const float* __restrict__ bq, float* __restrict__ qbuf) {
  __shared__ float hl[H_];
  int b = blockIdx.x, j = threadIdx.x;
  hl[j] = hfin[b * H_ + j];
  __syncthreads();
  float s = bq[j];
  const float* w = Wq + j * H_;
  for (int k = 0; k < H_; ++k) s += hl[k] * w[k];
  qbuf[b * H_ + j] = s;
}

// ---------------- K2: u = tanh(enc_out@Wref^T + bref + q) @ V (fused) ----------
__launch_bounds__(512)
__global__ void k2_att(const unsigned short* __restrict__ enc_out,
                       const unsigned short* __restrict__ Wrefb,
                       const float* __restrict__ qbuf, const float* __restrict__ bref,
                       const float* __restrict__ V, float* __restrict__ ubuf) {
  __shared__ unsigned short Bs[128 * HROW];
  __shared__ float qs[128], Vs[128];
  int tid = threadIdx.x;
  int wave = tid >> 6, lane = tid & 63, quad = lane >> 4, l16 = lane & 15;
  int rowblk = blockIdx.x >> 1, nb = blockIdx.x & 1;
  int b = rowblk >> 2;
  {  // stage Wref block [nb*128 .. +128) x 256 into LDS
    int nl = tid >> 2, seg = tid & 3;
    const unsigned short* src = Wrefb + (nb * 128 + nl) * H_ + seg * 64;
    unsigned short* dst = Bs + nl * HROW + seg * 64;
#pragma unroll
    for (int i = 0; i < 8; ++i) *(u16x8*)(dst + i * 8) = *(const u16x8*)(src + i * 8);
  }
  if (tid < 128) {
    int j = nb * 128 + tid;
    qs[tid] = qbuf[b * H_ + j] + bref[j];
    Vs[tid] = V[j];
  }
  __syncthreads();
  int rw = rowblk * 128 + wave * 16 + l16;  // global (b,s) row
  const f32x4 z4 = {0.f, 0.f, 0.f, 0.f};
  f32x4 acc[8];
#pragma unroll
  for (int kt = 0; kt < 8; ++kt) {
    bf16x8 af = *(const bf16x8*)(enc_out + (size_t)rw * H_ + kt * 32 + quad * 8);
#pragma unroll
    for (int nt = 0; nt < 8; ++nt) {
      bf16x8 bfr = *(const bf16x8*)(Bs + (nt * 16 + l16) * HROW + kt * 32 + quad * 8);
      acc[nt] = __builtin_amdgcn_mfma_f32_16x16x32_bf16(af, bfr, (kt == 0) ? z4 : acc[nt],
                                                        0, 0, 0);
    }
  }
  float part[4] = {0.f, 0.f, 0.f, 0.f};
#pragma unroll
  for (int nt = 0; nt < 8; ++nt) {
    float qv = qs[nt * 16 + l16], vv = Vs[nt * 16 + l16];
#pragma unroll
    for (int r = 0; r < 4; ++r) part[r] += tanh_(acc[nt][r] + qv) * vv;
  }
#pragma unroll
  for (int m = 1; m < 16; m <<= 1) {
#pragma unroll
    for (int r = 0; r < 4; ++r) part[r] += __shfl_xor(part[r], m, 64);
  }
  if (l16 == 0) {
    int s0 = (rowblk & 3) * 128 + wave * 16 + quad * 4;
#pragma unroll
    for (int r = 0; r < 4; ++r) atomicAdd(&ubuf[b * S_ + s0 + r], part[r]);
  }
}

// ---------------- K3: softmax + glimpse + decoder head ----------------
__global__ void k3_head(const float* __restrict__ ubuf,
                        const unsigned short* __restrict__ enc_out,
                        const float* __restrict__ Wd1, const float* __restrict__ Wd2,
                        float* __restrict__ out) {
  __shared__ float sm[512];
  __shared__ float red[256];
  __shared__ float gl[256];
  int b = blockIdx.x, tid = threadIdx.x;
  float u0 = ubuf[b * S_ + tid], u1 = ubuf[b * S_ + 256 + tid];
  red[tid] = fmaxf(u0, u1);
  __syncthreads();
  for (int s = 128; s > 0; s >>= 1) {
    if (tid < s) red[tid] = fmaxf(red[tid], red[tid + s]);
    __syncthreads();
  }
  float mx = red[0];
  __syncthreads();
  float e0 = __expf(u0 - mx), e1 = __expf(u1 - mx);
  red[tid] = e0 + e1;
  __syncthreads();
  for (int s = 128; s > 0; s >>= 1) {
    if (tid < s) red[tid] += red[tid + s];
    __syncthreads();
  }
  float inv = 1.f / red[0];
  sm[tid] = e0 * inv;
  sm[256 + tid] = e1 * inv;
  __syncthreads();
  float g = 0.f;
  const unsigned short* eo = enc_out + (size_t)b * S_ * H_ + tid;
  for (int s = 0; s < S_; ++s) g += sm[s] * bf2f(eo[(size_t)s * H_]);
  gl[tid] = g;
  __syncthreads();
  float y = 0.f;
  const float* w = Wd1 + tid * H_;
  for (int j = 0; j < H_; ++j) y += w[j] * gl[j];
  y = fmaxf(y, 0.f) * Wd2[tid];
  red[tid] = y;
  __syncthreads();
  for (int s = 128; s > 0; s >>= 1) {
    if (tid < s) red[tid] += red[tid + s];
    __syncthreads();
  }
  if (tid == 0) out[b] = red[0];
}

extern "C" void kernel_launch(void* const* d_in, const int* in_sizes, int n_in,
                              void* d_out, int out_size, void* d_ws, size_t ws_size,
                              hipStream_t stream) {
  (void)in_sizes; (void)n_in; (void)out_size; (void)ws_size;
  const float* inp    = (const float*)d_in[0];
  const float* W_emb  = (const float*)d_in[1];
  const float* dec_in = (const float*)d_in[2];
  const float* eWih   = (const float*)d_in[3];
  const float* eWhh   = (const float*)d_in[4];
  const float* ebih   = (const float*)d_in[5];
  const float* ebhh   = (const float*)d_in[6];
  const float* pWih   = (const float*)d_in[7];
  const float* pWhh   = (const float*)d_in[8];
  const float* pbih   = (const float*)d_in[9];
  const float* pbhh   = (const float*)d_in[10];
  const float* Wq     = (const float*)d_in[11];
  const float* bq     = (const float*)d_in[12];
  const float* Wref   = (const float*)d_in[13];
  const float* bref   = (const float*)d_in[14];
  const float* V      = (const float*)d_in[15];
  const float* Wd1    = (const float*)d_in[16];
  const float* Wd2    = (const float*)d_in[17];
  float* out = (float*)d_out;

  char* ws = (char*)d_ws;
  unsigned short* enc_out = (unsigned short*)(ws + OFF_ENC);
  unsigned short* WhhE    = (unsigned short*)(ws + OFF_WHHE);
  unsigned short* WhhP    = (unsigned short*)(ws + OFF_WHHP);
  unsigned short* Wrefb   = (unsigned short*)(ws + OFF_WREF);
  float* Menc  = (float*)(ws + OFF_MENC);
  float* biasE = (float*)(ws + OFF_BIASE);
  float* xpv   = (float*)(ws + OFF_XPV);
  unsigned int* flags = (unsigned int*)(ws + OFF_FLAGS);
  float* hfin = (float*)(ws + OFF_HFIN);
  float* qbuf = (float*)(ws + OFF_QBUF);
  float* ubuf = (float*)(ws + OFF_UBUF);

  hipLaunchKernelGGL(k0_prep, dim3(256), dim3(256), 0, stream,
                     eWih, eWhh, ebih, ebhh, pWih, pWhh, pbih, pbhh, W_emb, dec_in,
                     Wref, WhhE, WhhP, Wrefb, Menc, biasE, xpv, flags, ubuf);
  hipLaunchKernelGGL(k1_lstm, dim3(16), dim3(512), 0, stream,
                     inp, WhhE, WhhP, Menc, biasE, xpv, enc_out, hfin);
  hipLaunchKernelGGL(k1b_q, dim3(256), dim3(256), 0, stream, hfin, Wq, bq, qbuf);
  hipLaunchKernelGGL(k2_att, dim3(2048), dim3(512), 0, stream,
                     enc_out, Wrefb, qbuf, bref, V, ubuf);
  hipLaunchKernelGGL(k3_head, dim3(256), dim3(256), 0, stream,
                     ubuf, enc_out, Wd1, Wd2, out);
}

// Round 10
// 3368.567 us; speedup vs baseline: 3.1832x; 3.1832x over previous
//
#include <hip/hip_runtime.h>

#define B_ 256
#define S_ 512
#define E_ 128
#define H_ 256
#define FH_ 1024
#define HROW 264  // 256 + 8 pad (shorts) -> row offset 132 dwords = 4 mod 32, conflict-free

typedef __bf16 bf16x8 __attribute__((ext_vector_type(8)));
typedef float f32x4 __attribute__((ext_vector_type(4)));
typedef unsigned short u16x4 __attribute__((ext_vector_type(4)));
typedef unsigned short u16x8 __attribute__((ext_vector_type(8)));
typedef unsigned long long u64_;

__device__ __forceinline__ unsigned short f2bf(float f) {
  union { float f; unsigned int u; } a; a.f = f;
  unsigned int u = a.u;
  u += 0x7fffu + ((u >> 16) & 1u);  // RNE
  return (unsigned short)(u >> 16);
}
__device__ __forceinline__ float bf2f(unsigned short v) {
  union { unsigned int u; float f; } a; a.u = ((unsigned int)v) << 16;
  return a.f;
}
__device__ __forceinline__ float sigm(float x) { return 1.f / (1.f + __expf(-x)); }
__device__ __forceinline__ float tanh_(float x) {
  float e = __expf(2.f * x);
  return 1.f - 2.f / (e + 1.f);
}

// ---------------- workspace layout (bytes) ----------------
#define OFF_ENC    ((size_t)0)          // enc_out bf16 [256][512][256]  67108864
#define OFF_WHHE   ((size_t)67108864)   // enc_Whh bf16 [1024][256]        524288
#define OFF_WHHP   ((size_t)67633152)   // pb_Whh  bf16                    524288
#define OFF_WREF   ((size_t)68157440)   // Wref    bf16 [256][256]         131072
#define OFF_MENC   ((size_t)68288512)   // M = enc_Wih@W_emb f32 [1024][2]   8192
#define OFF_BIASE  ((size_t)68296704)   // enc_bih+enc_bhh f32 [1024]        4096
#define OFF_XPV    ((size_t)68300800)   // pb x-projection f32 [1024]        4096
#define OFF_FLAGS  ((size_t)68304896)   // u32 flags [16][2][8] per-wave     1024
#define OFF_HX     ((size_t)68305920)   // h exchange bf16 [2][16][2][128][16] 262144
#define OFF_HFIN   ((size_t)68568064)   // final h f32 [256][256]          262144
#define OFF_QBUF   ((size_t)68830208)   // q f32 [256][256]                262144
#define OFF_UBUF   ((size_t)69092352)   // u f32 [256][512]                524288

// ---------------- K0: prep (weight conversion, folded projections, zeroing) ----
__global__ void k0_prep(const float* __restrict__ eWih, const float* __restrict__ eWhh,
                        const float* __restrict__ ebih, const float* __restrict__ ebhh,
                        const float* __restrict__ pWih, const float* __restrict__ pWhh,
                        const float* __restrict__ pbih, const float* __restrict__ pbhh,
                        const float* __restrict__ W_emb, const float* __restrict__ dec_in,
                        const float* __restrict__ Wref,
                        unsigned short* __restrict__ WhhE, unsigned short* __restrict__ WhhP,
                        unsigned short* __restrict__ Wrefb,
                        float* __restrict__ Menc, float* __restrict__ biasE,
                        float* __restrict__ xpv,
                        unsigned int* __restrict__ flags, float* __restrict__ ubuf,
                        unsigned short* __restrict__ hx) {
  int gid = blockIdx.x * blockDim.x + threadIdx.x;
  int NT = gridDim.x * blockDim.x;
  for (int i = gid; i < FH_ * H_; i += NT) {
    WhhE[i] = f2bf(eWhh[i]);
    WhhP[i] = f2bf(pWhh[i]);
  }
  for (int i = gid; i < H_ * H_; i += NT) Wrefb[i] = f2bf(Wref[i]);
  for (int i = gid; i < B_ * S_; i += NT) ubuf[i] = 0.f;
  for (int i = gid; i < 131072; i += NT) hx[i] = 0;   // h(0) = 0 in both slots
  if (gid < 256) flags[gid] = 1u;                     // "h(0) published"
  if (gid < FH_) {
    int n = gid;
    float m0 = 0.f, m1 = 0.f, xs = 0.f;
    for (int e = 0; e < E_; ++e) {
      float w = eWih[n * E_ + e];
      m0 += w * W_emb[e * 2 + 0];
      m1 += w * W_emb[e * 2 + 1];
      xs += pWih[n * E_ + e] * dec_in[e];
    }
    Menc[n * 2 + 0] = m0;
    Menc[n * 2 + 1] = m1;
    biasE[n] = ebih[n] + ebhh[n];
    xpv[n] = xs + pbih[n] + pbhh[n];
  }
}

// ---------------- K1: persistent dual-LSTM, K-split pipelined exchange -------
// 32 WGs x 512 threads (R8 base = best measured 3.08ms). Pair of WGs (halves)
// split the 1024 gate columns; weights as 32 named f32x4 + asm pin (R8-proven).
// R8's 7200cy step = serialized exchange chain (FETCH 71MB == hx L3 loads).
// This round pipelines it:
//  - K-SPLIT: own 128 h-cols == half the K range -> own-K MFMAs run BEFORE
//    waiting on the peer; only peer-K waits. L3 load overlaps own-K GEMM.
//  - PER-WAVE FLAGS: peer wave w's hx is consumed only by our wave w, so each
//    wave stores hx, s_waitcnt vmcnt(0) on ITS OWN stores, sets flag_w --
//    no WG barrier before the flag. Consumers poll flag_w directly.
//  - 2 barriers/step (post-unpack, end) instead of 3 + tid0 spin.
__launch_bounds__(512)
__attribute__((amdgpu_waves_per_eu(2, 2)))
__global__ void k1_lstm(const float* __restrict__ inp,
                        const unsigned short* __restrict__ WhhE,
                        const unsigned short* __restrict__ WhhP,
                        const float* __restrict__ Menc, const float* __restrict__ biasE,
                        const float* __restrict__ xpv,
                        unsigned short* __restrict__ enc_out,
                        unsigned short* __restrict__ hx,
                        unsigned int* __restrict__ flags,
                        float* __restrict__ hfin) {
  __shared__ unsigned short hbuf[2][16 * HROW];  // h bf16 double buffer
  __shared__ float xin[2][16][2];
  const int tid = threadIdx.x;
  const int wave = tid >> 6, lane = tid & 63, quad = lane >> 4, l16 = lane & 15;
  const int blk = blockIdx.x;
  const int grp = (blk & 7) | ((blk >> 4) << 3);  // 0..15
  const int half = (blk >> 3) & 1;
  const int kloc = (wave << 4) | l16;    // 0..127 within half
  const int kcol = half * 128 + kloc;    // 0..255 global h-column
  const int okt = half * 128;            // own K base (shorts within a row)
  const int pkt = 128 - okt;             // peer K base

  for (int i = tid; i < 2 * 16 * HROW; i += 512) hbuf[0][i] = 0;
  if (tid < 32)
    xin[0][tid >> 1][tid & 1] = inp[((grp * 16 + (tid >> 1)) * S_ + 0) * 2 + (tid & 1)];

  float c[4] = {0.f, 0.f, 0.f, 0.f};
  float hreg[4] = {0.f, 0.f, 0.f, 0.f};
  // 32 named weight fragments: O = own-K half, P = peer-K half (128 VGPRs).
  f32x4 O00, O01, O02, O03, O10, O11, O12, O13;
  f32x4 O20, O21, O22, O23, O30, O31, O32, O33;
  f32x4 P00, P01, P02, P03, P10, P11, P12, P13;
  f32x4 P20, P21, P22, P23, P30, P31, P32, P33;
  float m0c[4], m1c[4], bc[4];
  unsigned int* myflagw = flags + (grp * 2 + half) * 8 + wave;
  unsigned int* pflagw = flags + (grp * 2 + (1 - half)) * 8 + wave;
  const f32x4 z4 = {0.f, 0.f, 0.f, 0.f};
  __syncthreads();

  int t = 0;
#pragma unroll 1
  for (int phase = 0; phase < 2; ++phase) {
    const unsigned short* W = phase ? WhhP : WhhE;
#define WLOAD(g)                                                        \
    {                                                                   \
      const unsigned short* wp = W + ((g) * 256 + kcol) * H_ + quad * 8; \
      O##g##0 = *(const f32x4*)(wp + okt + 0);                          \
      O##g##1 = *(const f32x4*)(wp + okt + 32);                         \
      O##g##2 = *(const f32x4*)(wp + okt + 64);                         \
      O##g##3 = *(const f32x4*)(wp + okt + 96);                         \
      P##g##0 = *(const f32x4*)(wp + pkt + 0);                          \
      P##g##1 = *(const f32x4*)(wp + pkt + 32);                         \
      P##g##2 = *(const f32x4*)(wp + pkt + 64);                         \
      P##g##3 = *(const f32x4*)(wp + pkt + 96);                         \
    }
    WLOAD(0) WLOAD(1) WLOAD(2) WLOAD(3)
#undef WLOAD
    asm volatile(""
                 : "+v"(O00), "+v"(O01), "+v"(O02), "+v"(O03),
                   "+v"(O10), "+v"(O11), "+v"(O12), "+v"(O13),
                   "+v"(O20), "+v"(O21), "+v"(O22), "+v"(O23),
                   "+v"(O30), "+v"(O31), "+v"(O32), "+v"(O33),
                   "+v"(P00), "+v"(P01), "+v"(P02), "+v"(P03),
                   "+v"(P10), "+v"(P11), "+v"(P12), "+v"(P13),
                   "+v"(P20), "+v"(P21), "+v"(P22), "+v"(P23),
                   "+v"(P30), "+v"(P31), "+v"(P32), "+v"(P33));
#pragma unroll
    for (int gg = 0; gg < 4; ++gg) {
      int n = gg * 256 + kcol;
      if (phase == 0) {
        m0c[gg] = Menc[n * 2 + 0]; m1c[gg] = Menc[n * 2 + 1]; bc[gg] = biasE[n];
      } else {
        m0c[gg] = 0.f; m1c[gg] = 0.f; bc[gg] = xpv[n];
      }
    }
#pragma unroll 1
    for (int step = 0; step < 512; ++step, ++t) {
      const int cur = t & 1, nxt = cur ^ 1;
      const unsigned short* hbc = &hbuf[cur][0];
      // ---- prefetch next x (latency hides under GEMM) ----
      float xpre = 0.f;
      if (phase == 0 && tid < 32) {
        int sN = (step < 511) ? step + 1 : 511;
        xpre = inp[((grp * 16 + (tid >> 1)) * S_ + sN) * 2 + (tid & 1)];
      }
      // ---- (1) own-K GEMM: no peer dependency ----
      f32x4 acc0 = z4, acc1 = z4, acc2 = z4, acc3 = z4;
#define MO(j)                                                                      \
      {                                                                            \
        bf16x8 Af = *(const bf16x8*)(hbc + l16 * HROW + okt + (j) * 32 + quad * 8);\
        acc0 = __builtin_amdgcn_mfma_f32_16x16x32_bf16(                            \
            Af, __builtin_bit_cast(bf16x8, O0##j), acc0, 0, 0, 0);                 \
        acc1 = __builtin_amdgcn_mfma_f32_16x16x32_bf16(                            \
            Af, __builtin_bit_cast(bf16x8, O1##j), acc1, 0, 0, 0);                 \
        acc2 = __builtin_amdgcn_mfma_f32_16x16x32_bf16(                            \
            Af, __builtin_bit_cast(bf16x8, O2##j), acc2, 0, 0, 0);                 \
        acc3 = __builtin_amdgcn_mfma_f32_16x16x32_bf16(                            \
            Af, __builtin_bit_cast(bf16x8, O3##j), acc3, 0, 0, 0);                 \
      }
      MO(0) MO(1) MO(2) MO(3)
#undef MO
      // ---- (2,3,4) per-wave poll + peer hx load + unpack into LDS ----
      {
        const unsigned int target = (unsigned int)(t + 1);
        while (__hip_atomic_load(pflagw, __ATOMIC_RELAXED, __HIP_MEMORY_SCOPE_AGENT) <
               target) {
          __builtin_amdgcn_s_sleep(1);
        }
        const unsigned short* ph =
            hx + ((size_t)(cur * 32 + grp * 2 + (1 - half))) * 2048;
        u64_ pv = __hip_atomic_load((const u64_*)(ph + tid * 4), __ATOMIC_RELAXED,
                                    __HIP_MEMORY_SCOPE_AGENT);
        int kp = tid >> 2, r0 = (tid & 3) * 4;
        unsigned short* dst = &hbuf[cur][0] + (1 - half) * 128 + kp;
        dst[(size_t)(r0 + 0) * HROW] = (unsigned short)(pv);
        dst[(size_t)(r0 + 1) * HROW] = (unsigned short)(pv >> 16);
        dst[(size_t)(r0 + 2) * HROW] = (unsigned short)(pv >> 32);
        dst[(size_t)(r0 + 3) * HROW] = (unsigned short)(pv >> 48);
      }
      __syncthreads();  // peer half of hbuf[cur] visible
      // ---- (5) peer-K GEMM ----
#define MP(j)                                                                      \
      {                                                                            \
        bf16x8 Af = *(const bf16x8*)(hbc + l16 * HROW + pkt + (j) * 32 + quad * 8);\
        acc0 = __builtin_amdgcn_mfma_f32_16x16x32_bf16(                            \
            Af, __builtin_bit_cast(bf16x8, P0##j), acc0, 0, 0, 0);                 \
        acc1 = __builtin_amdgcn_mfma_f32_16x16x32_bf16(                            \
            Af, __builtin_bit_cast(bf16x8, P1##j), acc1, 0, 0, 0);                 \
        acc2 = __builtin_amdgcn_mfma_f32_16x16x32_bf16(                            \
            Af, __builtin_bit_cast(bf16x8, P2##j), acc2, 0, 0, 0);                 \
        acc3 = __builtin_amdgcn_mfma_f32_16x16x32_bf16(                            \
            Af, __builtin_bit_cast(bf16x8, P3##j), acc3, 0, 0, 0);                 \
      }
      MP(0) MP(1) MP(2) MP(3)
#undef MP
      // ---- (6) gates ----
      unsigned short hb[4];
#pragma unroll
      for (int r = 0; r < 4; ++r) {
        int bl = quad * 4 + r;
        float x0 = xin[cur][bl][0], x1 = xin[cur][bl][1];
        float gi = acc0[r] + x0 * m0c[0] + x1 * m1c[0] + bc[0];
        float gf = acc1[r] + x0 * m0c[1] + x1 * m1c[1] + bc[1];
        float gc = acc2[r] + x0 * m0c[2] + x1 * m1c[2] + bc[2];
        float go = acc3[r] + x0 * m0c[3] + x1 * m1c[3] + bc[3];
        float cn = sigm(gf) * c[r] + sigm(gi) * tanh_(gc);
        c[r] = cn;
        hreg[r] = sigm(go) * tanh_(cn);
        hb[r] = f2bf(hreg[r]);
      }
      // ---- publish hx(t+1) FIRST (peer-latency-critical), per-wave flag ----
      {
        unsigned short* hxs = hx + ((size_t)(nxt * 32 + grp * 2 + half)) * 2048;
        u64_ pack = (u64_)hb[0] | ((u64_)hb[1] << 16) | ((u64_)hb[2] << 32) |
                    ((u64_)hb[3] << 48);
        __hip_atomic_store((u64_*)(hxs + kloc * 16 + quad * 4), pack,
                           __ATOMIC_RELAXED, __HIP_MEMORY_SCOPE_AGENT);
      }
      asm volatile("s_waitcnt vmcnt(0)");  // this wave's hx stores at L3
      if (lane == 0)
        __hip_atomic_store(myflagw, (unsigned int)(t + 2), __ATOMIC_RELAXED,
                           __HIP_MEMORY_SCOPE_AGENT);
      // ---- enc_out + own-half LDS h(t+1) + xin ----
      if (phase == 0) {
#pragma unroll
        for (int r = 0; r < 4; ++r)
          enc_out[(((size_t)(grp * 16 + quad * 4 + r) * S_ + step)) * H_ + kcol] = hb[r];
      }
#pragma unroll
      for (int r = 0; r < 4; ++r) hbuf[nxt][(quad * 4 + r) * HROW + kcol] = hb[r];
      if (phase == 0 && tid < 32) xin[nxt][tid >> 1][tid & 1] = xpre;
      __syncthreads();  // (8) own h(t+1) visible for next own-K GEMM
    }
  }
  // final h (fp32) for the attention query
#pragma unroll
  for (int r = 0; r < 4; ++r)
    hfin[(grp * 16 + quad * 4 + r) * H_ + kcol] = hreg[r];
}

// ---------------- K1b: q = h @ Wq^T + bq (fp32) ----------------
__global__ void k1b_q(const float* __restrict__ hfin, const float* __restrict__ Wq,
                      const float* __restrict__ bq, float* __restrict__ qbuf) {
  __shared__ float hl[H_];
  int b = blockIdx.x, j = threadIdx.x;
  hl[j] = hfin[b * H_ + j];
  __syncthreads();
  float s = bq[j];
  const float* w = Wq + j * H_;
  for (int k = 0; k < H_; ++k) s += hl[k] * w[k];
  qbuf[b * H_ + j] = s;
}

// ---------------- K2: u = tanh(enc_out@Wref^T + bref + q) @ V (fused) ----------
__launch_bounds__(512)
__global__ void k2_att(const unsigned short* __restrict__ enc_out,
                       const unsigned short* __restrict__ Wrefb,
                       const float* __restrict__ qbuf, const float* __restrict__ bref,
                       const float* __restrict__ V, float* __restrict__ ubuf) {
  __shared__ unsigned short Bs[128 * HROW];
  __shared__ float qs[128], Vs[128];
  int tid = threadIdx.x;
  int wave = tid >> 6, lane = tid & 63, quad = lane >> 4, l16 = lane & 15;
  int rowblk = blockIdx.x >> 1, nb = blockIdx.x & 1;
  int b = rowblk >> 2;
  {  // stage Wref block [nb*128 .. +128) x 256 into LDS
    int nl = tid >> 2, seg = tid & 3;
    const unsigned short* src = Wrefb + (nb * 128 + nl) * H_ + seg * 64;
    unsigned short* dst = Bs + nl * HROW + seg * 64;
#pragma unroll
    for (int i = 0; i < 8; ++i) *(u16x8*)(dst + i * 8) = *(const u16x8*)(src + i * 8);
  }
  if (tid < 128) {
    int j = nb * 128 + tid;
    qs[tid] = qbuf[b * H_ + j] + bref[j];
    Vs[tid] = V[j];
  }
  __syncthreads();
  int rw = rowblk * 128 + wave * 16 + l16;  // global (b,s) row
  const f32x4 z4 = {0.f, 0.f, 0.f, 0.f};
  f32x4 acc[8];
#pragma unroll
  for (int kt = 0; kt < 8; ++kt) {
    bf16x8 af = *(const bf16x8*)(enc_out + (size_t)rw * H_ + kt * 32 + quad * 8);
#pragma unroll
    for (int nt = 0; nt < 8; ++nt) {
      bf16x8 bfr = *(const bf16x8*)(Bs + (nt * 16 + l16) * HROW + kt * 32 + quad * 8);
      acc[nt] = __builtin_amdgcn_mfma_f32_16x16x32_bf16(af, bfr, (kt == 0) ? z4 : acc[nt],
                                                        0, 0, 0);
    }
  }
  float part[4] = {0.f, 0.f, 0.f, 0.f};
#pragma unroll
  for (int nt = 0; nt < 8; ++nt) {
    float qv = qs[nt * 16 + l16], vv = Vs[nt * 16 + l16];
#pragma unroll
    for (int r = 0; r < 4; ++r) part[r] += tanh_(acc[nt][r] + qv) * vv;
  }
#pragma unroll
  for (int m = 1; m < 16; m <<= 1) {
#pragma unroll
    for (int r = 0; r < 4; ++r) part[r] += __shfl_xor(part[r], m, 64);
  }
  if (l16 == 0) {
    int s0 = (rowblk & 3) * 128 + wave * 16 + quad * 4;
#pragma unroll
    for (int r = 0; r < 4; ++r) atomicAdd(&ubuf[b * S_ + s0 + r], part[r]);
  }
}

// ---------------- K3: softmax + glimpse + decoder head ----------------
__global__ void k3_head(const float* __restrict__ ubuf,
                        const unsigned short* __restrict__ enc_out,
                        const float* __restrict__ Wd1, const float* __restrict__ Wd2,
                        float* __restrict__ out) {
  __shared__ float sm[512];
  __shared__ float red[256];
  __shared__ float gl[256];
  int b = blockIdx.x, tid = threadIdx.x;
  float u0 = ubuf[b * S_ + tid], u1 = ubuf[b * S_ + 256 + tid];
  red[tid] = fmaxf(u0, u1);
  __syncthreads();
  for (int s = 128; s > 0; s >>= 1) {
    if (tid < s) red[tid] = fmaxf(red[tid], red[tid + s]);
    __syncthreads();
  }
  float mx = red[0];
  __syncthreads();
  float e0 = __expf(u0 - mx), e1 = __expf(u1 - mx);
  red[tid] = e0 + e1;
  __syncthreads();
  for (int s = 128; s > 0; s >>= 1) {
    if (tid < s) red[tid] += red[tid + s];
    __syncthreads();
  }
  float inv = 1.f / red[0];
  sm[tid] = e0 * inv;
  sm[256 + tid] = e1 * inv;
  __syncthreads();
  float g = 0.f;
  const unsigned short* eo = enc_out + (size_t)b * S_ * H_ + tid;
  for (int s = 0; s < S_; ++s) g += sm[s] * bf2f(eo[(size_t)s * H_]);
  gl[tid] = g;
  __syncthreads();
  float y = 0.f;
  const float* w = Wd1 + tid * H_;
  for (int j = 0; j < H_; ++j) y += w[j] * gl[j];
  y = fmaxf(y, 0.f) * Wd2[tid];
  red[tid] = y;
  __syncthreads();
  for (int s = 128; s > 0; s >>= 1) {
    if (tid < s) red[tid] += red[tid + s];
    __syncthreads();
  }
  if (tid == 0) out[b] = red[0];
}

extern "C" void kernel_launch(void* const* d_in, const int* in_sizes, int n_in,
                              void* d_out, int out_size, void* d_ws, size_t ws_size,
                              hipStream_t stream) {
  (void)in_sizes; (void)n_in; (void)out_size; (void)ws_size;
  const float* inp    = (const float*)d_in[0];
  const float* W_emb  = (const float*)d_in[1];
  const float* dec_in = (const float*)d_in[2];
  const float* eWih   = (const float*)d_in[3];
  const float* eWhh   = (const float*)d_in[4];
  const float* ebih   = (const float*)d_in[5];
  const float* ebhh   = (const float*)d_in[6];
  const float* pWih   = (const float*)d_in[7];
  const float* pWhh   = (const float*)d_in[8];
  const float* pbih   = (const float*)d_in[9];
  const float* pbhh   = (const float*)d_in[10];
  const float* Wq     = (const float*)d_in[11];
  const float* bq     = (const float*)d_in[12];
  const float* Wref   = (const float*)d_in[13];
  const float* bref   = (const float*)d_in[14];
  const float* V      = (const float*)d_in[15];
  const float* Wd1    = (const float*)d_in[16];
  const float* Wd2    = (const float*)d_in[17];
  float* out = (float*)d_out;

  char* ws = (char*)d_ws;
  unsigned short* enc_out = (unsigned short*)(ws + OFF_ENC);
  unsigned short* WhhE    = (unsigned short*)(ws + OFF_WHHE);
  unsigned short* WhhP    = (unsigned short*)(ws + OFF_WHHP);
  unsigned short* Wrefb   = (unsigned short*)(ws + OFF_WREF);
  float* Menc  = (float*)(ws + OFF_MENC);
  float* biasE = (float*)(ws + OFF_BIASE);
  float* xpv   = (float*)(ws + OFF_XPV);
  unsigned int* flags = (unsigned int*)(ws + OFF_FLAGS);
  unsigned short* hx  = (unsigned short*)(ws + OFF_HX);
  float* hfin = (float*)(ws + OFF_HFIN);
  float* qbuf = (float*)(ws + OFF_QBUF);
  float* ubuf = (float*)(ws + OFF_UBUF);

  hipLaunchKernelGGL(k0_prep, dim3(256), dim3(256), 0, stream,
                     eWih, eWhh, ebih, ebhh, pWih, pWhh, pbih, pbhh, W_emb, dec_in,
                     Wref, WhhE, WhhP, Wrefb, Menc, biasE, xpv, flags, ubuf, hx);
  hipLaunchKernelGGL(k1_lstm, dim3(32), dim3(512), 0, stream,
                     inp, WhhE, WhhP, Menc, biasE, xpv, enc_out, hx, flags, hfin);
  hipLaunchKernelGGL(k1b_q, dim3(256), dim3(256), 0, stream, hfin, Wq, bq, qbuf);
  hipLaunchKernelGGL(k2_att, dim3(2048), dim3(512), 0, stream,
                     enc_out, Wrefb, qbuf, bref, V, ubuf);
  hipLaunchKernelGGL(k3_head, dim3(256), dim3(256), 0, stream,
                     ubuf, enc_out, Wd1, Wd2, out);
}